// Round 9
// baseline (196.036 us; speedup 1.0000x reference)
//
#include <hip/hip_runtime.h>
#include <hip/hip_bf16.h>

#define PP     512
#define KK     64
#define BB     32
#define LLEN   2048
#define NPOS   (BB * LLEN)   // 65536

typedef __attribute__((ext_vector_type(8))) short short8;
typedef __attribute__((ext_vector_type(4))) float floatx4;

__device__ inline unsigned int pack_bf2(float lo, float hi) {
    __hip_bfloat162 h = __float22bfloat162_rn(make_float2(lo, hi));
    unsigned int u;
    __builtin_memcpy(&u, &h, 4);
    return u;   // low 16 = lo, high 16 = hi
}
__device__ inline float bf_lo(unsigned int v) { return __uint_as_float(v << 16); }
__device__ inline float bf_hi(unsigned int v) { return __uint_as_float(v & 0xffff0000u); }
__device__ inline ushort bf16u(float v) { return (ushort)(pack_bf2(v, 0.f) & 0xffffu); }

// ---------------------------------------------------------------------------
// K1: unified B-operand fragments, 128 cols: n<64 -> l_hat[n], n>=64 -> f2w[n-64].
// Bu4[f*128 + n] = 8 bf16 of src[n][8f..8f+7]  (f = 0..63)
// ---------------------------------------------------------------------------
__global__ void k1_prep(const float* __restrict__ C, const float* __restrict__ f2w,
                        ushort* __restrict__ Bu) {
    const int n = blockIdx.x;            // 0..127
    const float* src = (n < 64) ? (C + n * PP) : (f2w + (n - 64) * PP);
    const int t = threadIdx.x;
    float v0 = src[t];
    float v1 = src[t + 256];
    __shared__ float red[256];
    red[t] = v0 * v0 + v1 * v1;
    __syncthreads();
    for (int s = 128; s > 0; s >>= 1) {
        if (t < s) red[t] += red[t + s];
        __syncthreads();
    }
    const float inv = (n < 64) ? rsqrtf(red[0]) : 1.f;
    Bu[(((t >> 3)        * 128 + n) << 3) + (t & 7)] = bf16u(v0 * inv);
    Bu[((((t + 256) >> 3)) * 128 + n) * 8 + (t & 7)] = bf16u(v1 * inv);
}

// ---------------------------------------------------------------------------
// K2 MEGA: fused gather + dual GEMM (16x16x32 MFMA) + conv11 + max_k +
// block-softmax partial + pooling. Block = (b, 64-l chunk) + 8-row halo each
// side = 80 rows x 128 cols. K=512 in 2 chunks of 256 (sA 40KB single-buffer).
// After MFMA, sG/sE2 alias sA; conv/pool run from LDS. Writes 68-float
// partial per block: [0..63]=P_c, [64]=mx_c, [65]=sum_c.
// ---------------------------------------------------------------------------
__launch_bounds__(256)
__global__ void k2_mega(const int* __restrict__ x, const float* __restrict__ V,
                        const uint4* __restrict__ Bu4,
                        const float* __restrict__ f1w, const float* __restrict__ f1b,
                        float* __restrict__ pool) {
    __shared__ uint4 sA[80 * 32];      // 40 KB; later aliased by sG/sE2
    __shared__ int   stok[80];
    __shared__ float rnorm[80];
    __shared__ float smv[64];
    __shared__ float sp[64];
    __shared__ float sscal[2];
    __shared__ float sred[8][64];

    const int t   = threadIdx.x;
    const int b   = blockIdx.x >> 5;
    const int l0  = (blockIdx.x & 31) * 64;

    if (t < 80) {
        int l = l0 - 8 + t;
        l = l < 0 ? 0 : (l >= LLEN ? LLEN - 1 : l);
        stok[t] = x[b * LLEN + l];
    }
    __syncthreads();

    // ---- staging map: primary rows 0-63 (4 thr/row, 16 f4/chunk),
    //      secondary rows 64-79 (16 thr/row, 4 f4/chunk) ----
    const int pr = t >> 2,  pq = t & 3;
    const int sr = 64 + (t >> 4), sq = t & 15;
    const float4* prow = (const float4*)(V + (size_t)stok[pr] * PP);
    const float4* srow = (const float4*)(V + (size_t)stok[sr] * PP);

    // chunk-1 loads (back-to-back)
    float4 p1[16];
#pragma unroll
    for (int g = 0; g < 16; ++g) p1[g] = prow[pq * 16 + g];
    float4 s1[4];
#pragma unroll
    for (int g = 0; g < 4; ++g) s1[g] = srow[sq * 4 + g];

    // pack chunk-1 + norm partials (fp32, pre-round)
    float np = 0.f, ns = 0.f;
    const int pswz = pr & 7, sswz = sr & 7;
#pragma unroll
    for (int g = 0; g < 16; ++g) {
        const float4 a = p1[g];
        np = fmaf(a.x, a.x, fmaf(a.y, a.y, fmaf(a.z, a.z, fmaf(a.w, a.w, np))));
        uint2 w2; w2.x = pack_bf2(a.x, a.y); w2.y = pack_bf2(a.z, a.w);
        const int f = pq * 8 + (g >> 1);
        ((uint2*)&sA[pr * 32 + (f ^ pswz)])[g & 1] = w2;
    }
#pragma unroll
    for (int g = 0; g < 4; ++g) {
        const float4 a = s1[g];
        ns = fmaf(a.x, a.x, fmaf(a.y, a.y, fmaf(a.z, a.z, fmaf(a.w, a.w, ns))));
        uint2 w2; w2.x = pack_bf2(a.x, a.y); w2.y = pack_bf2(a.z, a.w);
        const int f = sq * 2 + (g >> 1);
        ((uint2*)&sA[sr * 32 + (f ^ sswz)])[g & 1] = w2;
    }

    // chunk-2 loads (in flight across chunk-1 MFMA)
    float4 p2[16];
#pragma unroll
    for (int g = 0; g < 16; ++g) p2[g] = prow[64 + pq * 16 + g];
    float4 s2[4];
#pragma unroll
    for (int g = 0; g < 4; ++g) s2[g] = srow[64 + sq * 4 + g];

    __syncthreads();   // sA chunk-1 ready

    const int lane = t & 63, wv = t >> 6;
    const int c15  = lane & 15;
    const int quad = lane >> 4;
    const int aswz = c15 & 7;
    const int n0   = (wv * 2) * 16 + c15;        // col of first n-tile
    const int n1   = (wv * 2 + 1) * 16 + c15;    // col of second n-tile

    floatx4 acc[5][2];
#pragma unroll
    for (int m = 0; m < 5; ++m) {
        acc[m][0] = (floatx4){0.f, 0.f, 0.f, 0.f};
        acc[m][1] = (floatx4){0.f, 0.f, 0.f, 0.f};
    }

    // ---- MFMA chunk 1 ----
#pragma unroll
    for (int ks = 0; ks < 8; ++ks) {
        const int fl = ks * 4 + quad;
        const uint4 b0 = Bu4[fl * 128 + n0];
        const uint4 b1 = Bu4[fl * 128 + n1];
        short8 bb0, bb1;
        __builtin_memcpy(&bb0, &b0, 16);
        __builtin_memcpy(&bb1, &b1, 16);
#pragma unroll
        for (int m = 0; m < 5; ++m) {
            const uint4 av = sA[(m * 16 + c15) * 32 + (fl ^ aswz)];
            short8 a8; __builtin_memcpy(&a8, &av, 16);
            acc[m][0] = __builtin_amdgcn_mfma_f32_16x16x32_bf16(a8, bb0, acc[m][0], 0, 0, 0);
            acc[m][1] = __builtin_amdgcn_mfma_f32_16x16x32_bf16(a8, bb1, acc[m][1], 0, 0, 0);
        }
    }
    __syncthreads();   // done reading chunk-1

    // ---- pack chunk-2 + finish norms ----
#pragma unroll
    for (int g = 0; g < 16; ++g) {
        const float4 a = p2[g];
        np = fmaf(a.x, a.x, fmaf(a.y, a.y, fmaf(a.z, a.z, fmaf(a.w, a.w, np))));
        uint2 w2; w2.x = pack_bf2(a.x, a.y); w2.y = pack_bf2(a.z, a.w);
        const int f = pq * 8 + (g >> 1);
        ((uint2*)&sA[pr * 32 + (f ^ pswz)])[g & 1] = w2;
    }
#pragma unroll
    for (int g = 0; g < 4; ++g) {
        const float4 a = s2[g];
        ns = fmaf(a.x, a.x, fmaf(a.y, a.y, fmaf(a.z, a.z, fmaf(a.w, a.w, ns))));
        uint2 w2; w2.x = pack_bf2(a.x, a.y); w2.y = pack_bf2(a.z, a.w);
        const int f = sq * 2 + (g >> 1);
        ((uint2*)&sA[sr * 32 + (f ^ sswz)])[g & 1] = w2;
    }
    np += __shfl_xor(np, 1, 64);
    np += __shfl_xor(np, 2, 64);
    if (pq == 0) rnorm[pr] = rsqrtf(np);
    ns += __shfl_xor(ns, 1, 64);
    ns += __shfl_xor(ns, 2, 64);
    ns += __shfl_xor(ns, 4, 64);
    ns += __shfl_xor(ns, 8, 64);
    if (sq == 0) rnorm[sr] = rsqrtf(ns);
    __syncthreads();   // sA chunk-2 ready

    // ---- MFMA chunk 2 ----
#pragma unroll
    for (int ks = 0; ks < 8; ++ks) {
        const int fl = ks * 4 + quad;
        const uint4 b0 = Bu4[(32 + fl) * 128 + n0];
        const uint4 b1 = Bu4[(32 + fl) * 128 + n1];
        short8 bb0, bb1;
        __builtin_memcpy(&bb0, &b0, 16);
        __builtin_memcpy(&bb1, &b1, 16);
#pragma unroll
        for (int m = 0; m < 5; ++m) {
            const uint4 av = sA[(m * 16 + c15) * 32 + (fl ^ aswz)];
            short8 a8; __builtin_memcpy(&a8, &av, 16);
            acc[m][0] = __builtin_amdgcn_mfma_f32_16x16x32_bf16(a8, bb0, acc[m][0], 0, 0, 0);
            acc[m][1] = __builtin_amdgcn_mfma_f32_16x16x32_bf16(a8, bb1, acc[m][1], 0, 0, 0);
        }
    }
    __syncthreads();   // sA dead -> alias sG/sE2

    // ---- write G (scaled, zero-masked) / E2 (raw) to LDS ----
    // slot layout: col c stored at (c&31)*2 + (c>>5) so uint read at
    // [row*33 + j] yields (lo=col j, hi=col j+32).
    ushort* sG  = (ushort*)sA;            // [80][66]
    ushort* sE2 = (ushort*)sA + 80 * 66;  // [80][66]
    const bool isG = (wv < 2);
#pragma unroll
    for (int m = 0; m < 5; ++m) {
#pragma unroll
        for (int i = 0; i < 2; ++i) {
            const int ccol = ((wv * 2 + i) * 16 + c15) & 63;
            const int slot = (ccol & 31) * 2 + (ccol >> 5);
#pragma unroll
            for (int reg = 0; reg < 4; ++reg) {
                const int row = m * 16 + quad * 4 + reg;
                float v = acc[m][i][reg];
                if (isG) {
                    const int l = l0 - 8 + row;
                    v = (l >= 0 && l < LLEN) ? v * rnorm[row] : 0.f;
                    sG[row * 66 + slot] = bf16u(v);
                } else {
                    sE2[row * 66 + slot] = bf16u(v);
                }
            }
        }
    }
    __syncthreads();

    // ---- conv11 + relu + max_k ----
    float w[11];
#pragma unroll
    for (int j = 0; j < 11; ++j) w[j] = f1w[j];
    const int j = t & 31;
    const int h = t >> 5;                  // 0..7
    const float bias0 = f1b[j], bias1 = f1b[j + 32];
    const uint* uG = (const uint*)sG;      // row stride 33 uints
#pragma unroll
    for (int i = 0; i < 8; ++i) {
        const int lr = i * 8 + h;          // core row 0..63; tile row lr+8
        float u0 = 0.f, u1 = 0.f;
#pragma unroll
        for (int tap = 0; tap < 11; ++tap) {
            const unsigned int v = uG[(lr + 3 + tap) * 33 + j];
            u0 = fmaf(bf_lo(v), w[tap], u0);
            u1 = fmaf(bf_hi(v), w[tap], u1);
        }
        float m = fmaxf(fmaxf(u0 + bias0, 0.f), fmaxf(u1 + bias1, 0.f));
#pragma unroll
        for (int off = 16; off > 0; off >>= 1)
            m = fmaxf(m, __shfl_xor(m, off, 64));
        if (j == 0) smv[lr] = m;
    }
    __syncthreads();

    // ---- block-local softmax partials ----
    if (t < 64) {
        float v = smv[t];
#pragma unroll
        for (int off = 32; off > 0; off >>= 1)
            v = fmaxf(v, __shfl_xor(v, off, 64));
        if (t == 0) sscal[0] = v;
    }
    __syncthreads();
    const float mx = sscal[0];
    if (t < 64) sp[t] = __expf(smv[t] - mx);
    __syncthreads();
    if (t < 64) {
        float s = sp[t];
#pragma unroll
        for (int off = 32; off > 0; off >>= 1)
            s += __shfl_xor(s, off, 64);
        if (t == 0) sscal[1] = s;
    }

    // ---- pooling from sE2 (raw emb . f2w) ----
    const uint* uE2 = (const uint*)sE2;
    float a0 = 0.f, a1 = 0.f;
#pragma unroll
    for (int i = 0; i < 8; ++i) {
        const int l = i * 8 + h;
        const float wgt = sp[l];
        const unsigned int e = uE2[(l + 8) * 33 + j];
        a0 = fmaf(wgt, bf_lo(e), a0);
        a1 = fmaf(wgt, bf_hi(e), a1);
    }
    sred[h][j]      = a0;
    sred[h][j + 32] = a1;
    __syncthreads();
    if (t < 64) {
        float r = 0.f;
#pragma unroll
        for (int hh = 0; hh < 8; ++hh) r += sred[hh][t];
        float* dst = pool + (size_t)blockIdx.x * 68;
        dst[t] = r;
        if (t == 0) { dst[64] = sscal[0]; dst[65] = sscal[1]; }
    }
}

// ---------------------------------------------------------------------------
// K6: combine 32 chunk-partials per b with online-softmax rescale + head bias.
// ---------------------------------------------------------------------------
__global__ void k6_final(const float* __restrict__ pool, const float* __restrict__ f2b,
                         float* __restrict__ out) {
    const int b = blockIdx.x;
    const int k = threadIdx.x;   // 64 threads
    float M = -1e30f;
#pragma unroll
    for (int c = 0; c < 32; ++c)
        M = fmaxf(M, pool[(size_t)(b * 32 + c) * 68 + 64]);
    float tot = 0.f, num = 0.f;
#pragma unroll
    for (int c = 0; c < 32; ++c) {
        const float* pc = pool + (size_t)(b * 32 + c) * 68;
        const float sc = __expf(pc[64] - M);
        tot = fmaf(sc, pc[65], tot);
        num = fmaf(sc, pc[k], num);
    }
    out[b * KK + k] = (num / tot) * (1.f / 2048.f) + f2b[k];
}

extern "C" void kernel_launch(void* const* d_in, const int* in_sizes, int n_in,
                              void* d_out, int out_size, void* d_ws, size_t ws_size,
                              hipStream_t stream) {
    const int*   x   = (const int*)d_in[0];
    const float* V   = (const float*)d_in[1];
    const float* C   = (const float*)d_in[2];
    const float* f1w = (const float*)d_in[3];
    const float* f1b = (const float*)d_in[4];
    const float* f2w = (const float*)d_in[5];
    const float* f2b = (const float*)d_in[6];
    float* out = (float*)d_out;

    float* ws = (float*)d_ws;
    ushort* Bu  = (ushort*)ws;                 // 65536 ushort (occupies 32768 floats)
    float* pool = ws + 32768;                  // 1024*68 floats

    k1_prep<<<128, 256, 0, stream>>>(C, f2w, Bu);
    k2_mega<<<BB * 32, 256, 0, stream>>>(x, V, (const uint4*)Bu, f1w, f1b, pool);
    k6_final<<<BB, 64, 0, stream>>>(pool, f2b, out);
}